// Round 1
// baseline (1564.848 us; speedup 1.0000x reference)
//
#include <hip/hip_runtime.h>
#include <math.h>

#define TOKENS 16384
#define HIDDEN 7168
#define NE     256
#define NGROUP 8
#define GSIZE  32   // experts per group
#define TOPKG  4
#define TOPK   8
#define TM     32   // tokens per block
#define BK     32   // k-tile

#define APITCH 36   // padded token pitch for A tile (144B, 16B aligned)
#define BPITCH 260  // padded expert pitch for B tile (1040B, 16B aligned)
#define SPITCH 257  // padded pitch for per-token score rows
// smem (floats), two overlapping phases:
//  phase1 (GEMM): As[BK][APITCH] @0 (1152), Bs[BK][BPITCH] @1152 (8320) -> 9472
//  phase2 (select): SFC[TM][SPITCH] @0 (8224), SIG[TM][SPITCH] @8224 -> 16448
#define SMEM_FLOATS 16448

__global__ __launch_bounds__(256, 2)
void gate_kernel(const float* __restrict__ X,
                 const float* __restrict__ W,
                 const float* __restrict__ bias,
                 float* __restrict__ out)
{
    __shared__ __align__(16) float smem[SMEM_FLOATS];
    const int tid = threadIdx.x;
    const int t0  = blockIdx.x * TM;

    // staging map: thread loads row (tid>>3), 16B chunk at col (tid&7)*4
    const int la_t = tid >> 3;        // 0..31
    const int la_k = (tid & 7) << 2;  // 0,4,...,28
    // compute map: 4 tokens x 8 experts per thread
    const int tx = tid & 31;          // experts tx*8 .. tx*8+7
    const int ty = tid >> 5;          // tokens ty*4 .. ty*4+3

    float acc[4][8];
    #pragma unroll
    for (int i = 0; i < 4; i++)
        #pragma unroll
        for (int j = 0; j < 8; j++) acc[i][j] = 0.f;

    const float* Aptr = X + (size_t)(t0 + la_t) * HIDDEN + la_k;
    const float* Bptr = W + (size_t)la_t * HIDDEN + la_k;

    for (int k0 = 0; k0 < HIDDEN; k0 += BK) {
        // global loads into regs (A: 1 float4, B: 8 float4 across expert rows)
        float4 av = *(const float4*)(Aptr + k0);
        float4 bv[8];
        #pragma unroll
        for (int i = 0; i < 8; i++)
            bv[i] = *(const float4*)(Bptr + (size_t)i * 32 * HIDDEN + k0);

        __syncthreads();  // previous tile's compute done before overwrite
        #pragma unroll
        for (int j = 0; j < 4; j++)
            smem[(la_k + j) * APITCH + la_t] = ((const float*)&av)[j];
        #pragma unroll
        for (int i = 0; i < 8; i++)
            #pragma unroll
            for (int j = 0; j < 4; j++)
                smem[1152 + (la_k + j) * BPITCH + (la_t + 32 * i)] =
                    ((const float*)&bv[i])[j];
        __syncthreads();

        #pragma unroll
        for (int kk = 0; kk < BK; kk++) {
            float4 a4 = *(const float4*)&smem[kk * APITCH + (ty << 2)];
            float4 b0 = *(const float4*)&smem[1152 + kk * BPITCH + (tx << 3)];
            float4 b1 = *(const float4*)&smem[1152 + kk * BPITCH + (tx << 3) + 4];
            const float a[4] = {a4.x, a4.y, a4.z, a4.w};
            const float b[8] = {b0.x, b0.y, b0.z, b0.w, b1.x, b1.y, b1.z, b1.w};
            #pragma unroll
            for (int i = 0; i < 4; i++)
                #pragma unroll
                for (int j = 0; j < 8; j++)
                    acc[i][j] = fmaf(a[i], b[j], acc[i][j]);
        }
    }
    __syncthreads();  // all tile reads done; safe to overwrite with score arrays

    // epilogue: sigmoid (+bias) into LDS
    #pragma unroll
    for (int i = 0; i < 4; i++) {
        const int t = (ty << 2) + i;
        #pragma unroll
        for (int j = 0; j < 8; j++) {
            const int e = (tx << 3) + j;
            const float sig = 1.0f / (1.0f + expf(-acc[i][j]));
            smem[8224 + t * SPITCH + e] = sig;          // unmasked sigmoid
            smem[t * SPITCH + e]        = sig + bias[e]; // scores_for_choice
        }
    }
    __syncthreads();

    // group-limited top-k selection, one thread per token
    if (tid < TM) {
        float* sfc = &smem[tid * SPITCH];
        const float* sig = &smem[8224 + tid * SPITCH];

        // per-group sum of top-2
        float gs[NGROUP];
        #pragma unroll
        for (int g = 0; g < NGROUP; g++) {
            float m1 = -INFINITY, m2 = -INFINITY;
            for (int x = 0; x < GSIZE; x++) {
                const float v = sfc[g * GSIZE + x];
                if (v > m1) { m2 = m1; m1 = v; }
                else if (v > m2) { m2 = v; }
            }
            gs[g] = m1 + m2;
        }
        // top-4 groups (strict >, ascending scan == stable top_k tie-break)
        bool gsel[NGROUP] = {false, false, false, false, false, false, false, false};
        for (int r = 0; r < TOPKG; r++) {
            int bi = 0; float bv = -INFINITY;
            for (int g = 0; g < NGROUP; g++)
                if (!gsel[g] && gs[g] > bv) { bv = gs[g]; bi = g; }
            gsel[bi] = true;
        }
        // mask: unselected groups -> 0.0 (exactly like scores*0 mask)
        for (int g = 0; g < NGROUP; g++)
            if (!gsel[g])
                for (int x = 0; x < GSIZE; x++) sfc[g * GSIZE + x] = 0.0f;

        // top-8 experts, stable
        int sel[TOPK]; float w[TOPK]; float sum = 0.f;
        for (int r = 0; r < TOPK; r++) {
            int bi = 0; float bv = sfc[0];
            for (int e = 1; e < NE; e++) {
                const float v = sfc[e];
                if (v > bv) { bv = v; bi = e; }
            }
            sel[r] = bi;
            sfc[bi] = -INFINITY;
            w[r] = sig[bi];   // weight from UNMASKED sigmoid score
            sum += w[r];
        }
        const float scale = 2.5f / (sum + 1e-20f);
        const int gt = t0 + tid;
        #pragma unroll
        for (int r = 0; r < TOPK; r++) {
            out[(size_t)gt * TOPK + r] = w[r] * scale;
            out[(size_t)TOKENS * TOPK + (size_t)gt * TOPK + r] = (float)sel[r];
        }
    }
}

extern "C" void kernel_launch(void* const* d_in, const int* in_sizes, int n_in,
                              void* d_out, int out_size, void* d_ws, size_t ws_size,
                              hipStream_t stream) {
    const float* X  = (const float*)d_in[0];  // [16384, 7168] fp32
    const float* W  = (const float*)d_in[1];  // [256, 7168] fp32
    const float* eb = (const float*)d_in[2];  // [256] fp32
    float* out = (float*)d_out;               // [16384*8 weights][16384*8 indices]

    dim3 grid(TOKENS / TM);
    dim3 block(256);
    hipLaunchKernelGGL(gate_kernel, grid, block, 0, stream, X, W, eb, out);
}

// Round 2
// 821.316 us; speedup vs baseline: 1.9053x; 1.9053x over previous
//
#include <hip/hip_runtime.h>
#include <math.h>
#include <stdint.h>

#define TOKENS 16384
#define HIDDEN 7168
#define NE     256
#define NGROUP 8
#define GSIZE  32
#define TOPKG  4
#define TOPK   8

#define KSPLIT 2
#define TM     128
#define BK     32
#define KC_TOTAL (HIDDEN / BK)            // 224
#define KC_SLICE (KC_TOTAL / KSPLIT)      // 112

// ws layout: [0, WPLANES_BYTES): fp16 W planes in frag order; then fp32 partials [2][16384][256]
#define WPLANES_BYTES ((size_t)KC_TOTAL * 32 * 1024)   // 7,340,032

typedef _Float16 half8 __attribute__((ext_vector_type(8)));
typedef float    floatx4 __attribute__((ext_vector_type(4)));
typedef unsigned int u32;
#define GAS __attribute__((address_space(1)))
#define LAS __attribute__((address_space(3)))

// ---------------------------------------------------------------------------
// Prep: split W fp32 -> (wh, wl*2048) fp16 planes, stored frag-ordered:
// half-unit offset = kc*16384 + p*8192 + et*512 + lane*8 + j
// where e = 16*et + (lane&15), k = 32*kc + (lane>>4)*8 + j
// ---------------------------------------------------------------------------
__global__ void prep_w(const float* __restrict__ W, _Float16* __restrict__ wp) {
    const int c = blockIdx.x * 128 + threadIdx.x;   // 0..895 (k-chunk of 8)
    const int e = blockIdx.y;                        // 0..255
    const int k = c * 8;
    const float* src = W + (size_t)e * HIDDEN + k;
    float4 v0 = *(const float4*)src;
    float4 v1 = *(const float4*)(src + 4);
    float xv[8] = {v0.x, v0.y, v0.z, v0.w, v1.x, v1.y, v1.z, v1.w};
    half8 h, l;
    #pragma unroll
    for (int j = 0; j < 8; j++) {
        _Float16 hh = (_Float16)xv[j];
        h[j] = hh;
        l[j] = (_Float16)((xv[j] - (float)hh) * 2048.0f);
    }
    const int kc = c >> 2;
    const int g  = c & 3;
    const int lane = g * 16 + (e & 15);
    const int et   = e >> 4;
    const size_t base = (size_t)kc * 16384 + (size_t)et * 512 + (size_t)lane * 8;
    *(half8*)(wp + base)        = h;   // plane 0 (hi)
    *(half8*)(wp + base + 8192) = l;   // plane 1 (lo, *2048)
}

// ---------------------------------------------------------------------------
// GEMM: block = 128 tokens x 256 experts x K/2, 512 threads (8 waves).
// Wave (wr=w&1, wc=w>>1): 64 tokens x 64 experts = 4x4 tiles of 16x16x32 f16.
// LDS: A planes 16 KB @0 (halves [0,8192)), B planes 32 KB @16 KB (halves [8192,24576))
// ---------------------------------------------------------------------------
__global__ __launch_bounds__(512, 2)
void gemm_kernel(const float* __restrict__ X, const _Float16* __restrict__ wp,
                 float* __restrict__ partial) {
    __shared__ __align__(16) _Float16 smem[24576];   // 48 KB

    const int tid = threadIdx.x;
    const int b   = blockIdx.x;
    const int mt0 = b >> 1;          // 0..127
    const int ks  = b & 1;
    const int t0  = mt0 * TM;
    const int kc0 = ks * KC_SLICE;

    const int w    = tid >> 6;       // wave 0..7
    const int lane = tid & 63;
    const int wr   = w & 1;          // token half (64)
    const int wc   = w >> 1;         // expert quarter (64)

    // A staging map: thread -> (token at, k-chunk-of-8 ac)
    const int at = tid >> 2;         // 0..127
    const int ac = tid & 3;          // 0..3
    const float* Xrow = X + (size_t)(t0 + at) * HIDDEN + ac * 8;
    const int awoff = (at >> 4) * 512 + (16 * ac + (at & 15)) * 8;  // half units

    floatx4 acc0[4][4], acc1[4][4];
    #pragma unroll
    for (int i = 0; i < 4; i++)
        #pragma unroll
        for (int j = 0; j < 4; j++) {
            acc0[i][j] = (floatx4){0.f, 0.f, 0.f, 0.f};
            acc1[i][j] = (floatx4){0.f, 0.f, 0.f, 0.f};
        }

    const char* wbase = (const char*)wp;

    for (int kc = kc0; kc < kc0 + KC_SLICE; kc++) {
        __syncthreads();   // prior iter's frag reads done before overwrite

        // ---- B: async copy 32 KB contiguous (already frag-ordered in ws) ----
        const char* wsrc = wbase + (size_t)kc * 32768;
        char* bdst = (char*)smem + 16384;
        #pragma unroll
        for (int i = 0; i < 4; i++) {
            const int o = (tid + 512 * i) * 16;
            __builtin_amdgcn_global_load_lds((GAS const u32*)(wsrc + o),
                                             (LAS u32*)(bdst + o), 16, 0, 0);
        }

        // ---- A: load 8 fp32, split to 2 fp16 planes, frag-ordered writes ----
        const float* xp = Xrow + (size_t)kc * BK;
        float4 v0 = *(const float4*)xp;
        float4 v1 = *(const float4*)(xp + 4);
        float xv[8] = {v0.x, v0.y, v0.z, v0.w, v1.x, v1.y, v1.z, v1.w};
        half8 ahh, ahl;
        #pragma unroll
        for (int j = 0; j < 8; j++) {
            _Float16 hh = (_Float16)xv[j];
            ahh[j] = hh;
            ahl[j] = (_Float16)((xv[j] - (float)hh) * 2048.0f);
        }
        *(half8*)(smem + awoff)        = ahh;
        *(half8*)(smem + 4096 + awoff) = ahl;

        __syncthreads();   // staging (incl. global_load_lds vmcnt) drained

        // ---- fragments + 48 MFMA ----
        const _Float16* Ah = smem + (4 * wr) * 512;
        const _Float16* Bb = smem + 8192 + (4 * wc) * 512;
        half8 bh[4], bl[4];
        #pragma unroll
        for (int et = 0; et < 4; et++) {
            bh[et] = *(const half8*)(Bb + et * 512 + lane * 8);
            bl[et] = *(const half8*)(Bb + 8192 + et * 512 + lane * 8);
        }
        #pragma unroll
        for (int mt = 0; mt < 4; mt++) {
            half8 ah = *(const half8*)(Ah + mt * 512 + lane * 8);
            half8 al = *(const half8*)(Ah + 4096 + mt * 512 + lane * 8);
            #pragma unroll
            for (int et = 0; et < 4; et++) {
                acc0[mt][et] = __builtin_amdgcn_mfma_f32_16x16x32_f16(ah, bh[et], acc0[mt][et], 0, 0, 0);
                acc1[mt][et] = __builtin_amdgcn_mfma_f32_16x16x32_f16(ah, bl[et], acc1[mt][et], 0, 0, 0);
                acc1[mt][et] = __builtin_amdgcn_mfma_f32_16x16x32_f16(al, bh[et], acc1[mt][et], 0, 0, 0);
            }
        }
    }

    // ---- epilogue: combine planes, write fp32 partial [ks][t][e] ----
    float* P = partial + (size_t)ks * TOKENS * NE;
    const int rbase0 = t0 + 64 * wr;
    const int cbase0 = 64 * wc;
    const float inv = 1.0f / 2048.0f;
    #pragma unroll
    for (int mt = 0; mt < 4; mt++)
        #pragma unroll
        for (int et = 0; et < 4; et++) {
            floatx4 r = acc0[mt][et] + acc1[mt][et] * inv;
            const int col = cbase0 + 16 * et + (lane & 15);
            const int row = rbase0 + 16 * mt + (lane >> 4) * 4;
            #pragma unroll
            for (int rr = 0; rr < 4; rr++)
                P[(size_t)(row + rr) * NE + col] = r[rr];
        }
}

// ---------------------------------------------------------------------------
// Selection: block = 32 tokens, 64 threads. sfc in LDS; group-limited top-k.
// ---------------------------------------------------------------------------
__global__ __launch_bounds__(64)
void select_kernel(const float* __restrict__ partial, const float* __restrict__ bias,
                   float* __restrict__ out) {
    __shared__ float sfc[32][257];
    const int tid = threadIdx.x;
    const int t0  = blockIdx.x * 32;
    const float* P0 = partial;
    const float* P1 = partial + (size_t)TOKENS * NE;

    for (int t = 0; t < 32; t++) {
        #pragma unroll
        for (int e0 = 0; e0 < NE; e0 += 64) {
            const int e = e0 + tid;
            const size_t idx = (size_t)(t0 + t) * NE + e;
            const float logit = P0[idx] + P1[idx];
            const float sig = 1.0f / (1.0f + expf(-logit));
            sfc[t][e] = sig + bias[e];
        }
    }
    __syncthreads();

    if (tid < 32) {
        float* s = sfc[tid];
        // group scores: sum of top-2 per group
        float gs[NGROUP];
        #pragma unroll
        for (int g = 0; g < NGROUP; g++) {
            float m1 = -INFINITY, m2 = -INFINITY;
            for (int x = 0; x < GSIZE; x++) {
                const float v = s[g * GSIZE + x];
                if (v > m1) { m2 = m1; m1 = v; }
                else if (v > m2) { m2 = v; }
            }
            gs[g] = m1 + m2;
        }
        bool gsel[NGROUP] = {false,false,false,false,false,false,false,false};
        for (int r = 0; r < TOPKG; r++) {
            int bi = 0; float bv = -INFINITY;
            for (int g = 0; g < NGROUP; g++)
                if (!gsel[g] && gs[g] > bv) { bv = gs[g]; bi = g; }
            gsel[bi] = true;
        }
        // top-8 experts over masked scores (mask applied on the fly; sfc kept
        // unmasked so weights for masked-but-selected experts stay exact)
        int sel[TOPK]; float wgt[TOPK]; float sum = 0.f;
        for (int r = 0; r < TOPK; r++) {
            int bi = 0; float bv = -INFINITY;
            for (int e = 0; e < NE; e++) {
                const float sv = s[e];
                const float v = (sv == -INFINITY) ? -INFINITY
                               : (gsel[e >> 5] ? sv : 0.0f);
                if (v > bv) { bv = v; bi = e; }
            }
            sel[r] = bi;
            wgt[r] = s[bi] - bias[bi];   // unmasked sigmoid score
            s[bi]  = -INFINITY;
            sum += wgt[r];
        }
        const float scale = 2.5f / (sum + 1e-20f);
        const int gt = t0 + tid;
        #pragma unroll
        for (int r = 0; r < TOPK; r++) {
            out[(size_t)gt * TOPK + r] = wgt[r] * scale;
            out[(size_t)TOKENS * TOPK + (size_t)gt * TOPK + r] = (float)sel[r];
        }
    }
}

extern "C" void kernel_launch(void* const* d_in, const int* in_sizes, int n_in,
                              void* d_out, int out_size, void* d_ws, size_t ws_size,
                              hipStream_t stream) {
    const float* X  = (const float*)d_in[0];
    const float* W  = (const float*)d_in[1];
    const float* eb = (const float*)d_in[2];
    float* out = (float*)d_out;

    _Float16* wp   = (_Float16*)d_ws;
    float* partial = (float*)((char*)d_ws + WPLANES_BYTES);

    hipLaunchKernelGGL(prep_w, dim3(7, 256), dim3(128), 0, stream, W, wp);
    hipLaunchKernelGGL(gemm_kernel, dim3(TM == 128 ? 256 : 256), dim3(512), 0, stream, X, wp, partial);
    hipLaunchKernelGGL(select_kernel, dim3(TOKENS / 32), dim3(64), 0, stream, partial, eb, out);
}

// Round 3
// 784.557 us; speedup vs baseline: 1.9946x; 1.0469x over previous
//
#include <hip/hip_runtime.h>
#include <math.h>
#include <stdint.h>

#define TOKENS 16384
#define HIDDEN 7168
#define NE     256
#define NGROUP 8
#define GSIZE  32
#define TOPKG  4
#define TOPK   8

#define KSPLIT 2
#define TM     64                         // tokens per block
#define BK     32
#define KC_TOTAL (HIDDEN / BK)            // 224
#define KC_SLICE (KC_TOTAL / KSPLIT)      // 112

// ws: [0, WPLANES_BYTES) fp16 W planes (frag order); then fp32 partials [2][16384][256]
#define WPLANES_BYTES ((size_t)KC_TOTAL * 32 * 1024)   // 7,340,032

typedef _Float16 half8 __attribute__((ext_vector_type(8)));
typedef float    floatx4 __attribute__((ext_vector_type(4)));
typedef unsigned int u32;
#define GAS __attribute__((address_space(1)))
#define LAS __attribute__((address_space(3)))

// ---------------------------------------------------------------------------
// Split W fp32 -> (wh, wl*2048) fp16 planes, frag-ordered per kc-block:
// half-offset = kc*16384 + plane*8192 + et*512 + (g*16 + (e&15))*8 + j
// where e = 16*et + (e&15), k = 32*kc + g*8 + j   (verified end-to-end in r2)
// ---------------------------------------------------------------------------
__global__ void prep_w(const float* __restrict__ W, _Float16* __restrict__ wp) {
    const int c = blockIdx.x * 128 + threadIdx.x;   // k-chunk of 8 (0..895)
    const int e = blockIdx.y;
    const float* src = W + (size_t)e * HIDDEN + c * 8;
    float4 v0 = *(const float4*)src;
    float4 v1 = *(const float4*)(src + 4);
    float xv[8] = {v0.x, v0.y, v0.z, v0.w, v1.x, v1.y, v1.z, v1.w};
    half8 h, l;
    #pragma unroll
    for (int j = 0; j < 8; j++) {
        _Float16 hh = (_Float16)xv[j];
        h[j] = hh;
        l[j] = (_Float16)((xv[j] - (float)hh) * 2048.0f);
    }
    const int kc = c >> 2;
    const int g  = c & 3;
    const int lane = g * 16 + (e & 15);
    const int et   = e >> 4;
    const size_t base = (size_t)kc * 16384 + (size_t)et * 512 + (size_t)lane * 8;
    *(half8*)(wp + base)        = h;
    *(half8*)(wp + base + 8192) = l;
}

// ---------------------------------------------------------------------------
// GEMM: block = 64 tokens x 256 experts x K/2. 256 threads = 4 waves.
// Wave w -> expert quarter (64 experts), all 64 tokens: 4x4 tiles of 16x16x32.
// LDS 40 KB: A planes [0,4096) halves, B planes [4096,20480).
// 2 blocks/CU co-resident -> barrier drains of one block hidden by the other.
// ---------------------------------------------------------------------------
__global__ __launch_bounds__(256, 2)
void gemm_kernel(const float* __restrict__ X, const _Float16* __restrict__ wp,
                 float* __restrict__ partial) {
    __shared__ __align__(16) _Float16 smem[20480];   // 40 KB

    const int tid  = threadIdx.x;
    const int b    = blockIdx.x;
    const int tb   = b >> 1;
    const int ks   = b & 1;          // XCD = b%8 -> each XCD sees ONE wp half (L2-resident)
    const int t0   = tb * TM;

    const int w    = tid >> 6;       // wave 0..3 -> expert quarter
    const int lane = tid & 63;

    // A staging map: thread -> token at = tid>>2 (coalesced 128B row chunks), k-granule ac
    const int at = tid >> 2;
    const int ac = tid & 3;
    const int awoff = (at >> 4) * 512 + (ac * 16 + (at & 15)) * 8;  // frag-order chunk
    const float* Xrow = X + (size_t)(t0 + at) * HIDDEN + ks * (HIDDEN / KSPLIT) + ac * 8;

    const char* wbase = (const char*)wp + (size_t)ks * KC_SLICE * 32768;

    floatx4 acc0[4][4], acc1[4][4];
    #pragma unroll
    for (int i = 0; i < 4; i++)
        #pragma unroll
        for (int j = 0; j < 4; j++) {
            acc0[i][j] = (floatx4){0.f, 0.f, 0.f, 0.f};
            acc1[i][j] = (floatx4){0.f, 0.f, 0.f, 0.f};
        }

    // software pipeline: A regs for iter 0 preloaded
    float4 v0 = *(const float4*)Xrow;
    float4 v1 = *(const float4*)(Xrow + 4);

    for (int i = 0; i < KC_SLICE; i++) {
        __syncthreads();   // prior iter's frag reads done before overwrite

        // ---- stage A: split prefetched regs into 2 fp16 planes, frag-order ----
        {
            float xv[8] = {v0.x, v0.y, v0.z, v0.w, v1.x, v1.y, v1.z, v1.w};
            half8 ahh, ahl;
            #pragma unroll
            for (int j = 0; j < 8; j++) {
                _Float16 hh = (_Float16)xv[j];
                ahh[j] = hh;
                ahl[j] = (_Float16)((xv[j] - (float)hh) * 2048.0f);
            }
            *(half8*)(smem + awoff)        = ahh;
            *(half8*)(smem + 2048 + awoff) = ahl;
        }

        // ---- stage B: async 32 KB, already frag-ordered in ws ----
        {
            const char* wsrc = wbase + (size_t)i * 32768;
            char* bdst = (char*)(smem + 4096);
            #pragma unroll
            for (int q = 0; q < 8; q++) {
                const int o = (tid + 256 * q) * 16;
                __builtin_amdgcn_global_load_lds((GAS const u32*)(wsrc + o),
                                                 (LAS u32*)(bdst + o), 16, 0, 0);
            }
        }

        __syncthreads();   // drains A lds-writes + B global_load_lds

        // ---- prefetch next iter's A into regs (hidden under MFMAs) ----
        if (i + 1 < KC_SLICE) {
            const float* xp = Xrow + (size_t)(i + 1) * BK;
            v0 = *(const float4*)xp;
            v1 = *(const float4*)(xp + 4);
        }

        // ---- fragments + 48 MFMA (dependent acc1 pairs separated by et sweep) ----
        const _Float16* Bb = smem + 4096 + w * 2048;   // expert quarter, plane0
        half8 bh[4], bl[4];
        #pragma unroll
        for (int et = 0; et < 4; et++) {
            bh[et] = *(const half8*)(Bb + et * 512 + lane * 8);
            bl[et] = *(const half8*)(Bb + 8192 + et * 512 + lane * 8);
        }
        #pragma unroll
        for (int mt = 0; mt < 4; mt++) {
            half8 ah = *(const half8*)(smem + mt * 512 + lane * 8);
            half8 al = *(const half8*)(smem + 2048 + mt * 512 + lane * 8);
            #pragma unroll
            for (int et = 0; et < 4; et++)
                acc0[mt][et] = __builtin_amdgcn_mfma_f32_16x16x32_f16(ah, bh[et], acc0[mt][et], 0, 0, 0);
            #pragma unroll
            for (int et = 0; et < 4; et++)
                acc1[mt][et] = __builtin_amdgcn_mfma_f32_16x16x32_f16(ah, bl[et], acc1[mt][et], 0, 0, 0);
            #pragma unroll
            for (int et = 0; et < 4; et++)
                acc1[mt][et] = __builtin_amdgcn_mfma_f32_16x16x32_f16(al, bh[et], acc1[mt][et], 0, 0, 0);
        }
    }

    // ---- epilogue: combine planes, write fp32 partials [ks][t][e] ----
    float* P = partial + (size_t)ks * TOKENS * NE;
    const float inv = 1.0f / 2048.0f;
    #pragma unroll
    for (int mt = 0; mt < 4; mt++)
        #pragma unroll
        for (int et = 0; et < 4; et++) {
            floatx4 r = acc0[mt][et] + acc1[mt][et] * inv;
            const int col = w * 64 + 16 * et + (lane & 15);
            const int row = t0 + 16 * mt + (lane >> 4) * 4;
            #pragma unroll
            for (int rr = 0; rr < 4; rr++)
                P[(size_t)(row + rr) * NE + col] = r[rr];
        }
}

// ---------------------------------------------------------------------------
// Selection: block = 32 tokens, 256 threads (parallel load), serial per-token
// group-limited top-k on lanes 0..31 (logic verified in r1/r2).
// ---------------------------------------------------------------------------
__global__ __launch_bounds__(256)
void select_kernel(const float* __restrict__ partial, const float* __restrict__ bias,
                   float* __restrict__ out) {
    __shared__ float sfc[32][257];
    const int tid = threadIdx.x;
    const int t0  = blockIdx.x * 32;
    const float* P0 = partial;
    const float* P1 = partial + (size_t)TOKENS * NE;

    for (int idx = tid; idx < 32 * NE; idx += 256) {
        const int t = idx >> 8;
        const int e = idx & 255;
        const size_t g = (size_t)(t0 + t) * NE + e;
        const float logit = P0[g] + P1[g];
        const float sig = 1.0f / (1.0f + expf(-logit));
        sfc[t][e] = sig + bias[e];
    }
    __syncthreads();

    if (tid < 32) {
        float* s = sfc[tid];
        float gs[NGROUP];
        #pragma unroll
        for (int g = 0; g < NGROUP; g++) {
            float m1 = -INFINITY, m2 = -INFINITY;
            for (int x = 0; x < GSIZE; x++) {
                const float v = s[g * GSIZE + x];
                if (v > m1) { m2 = m1; m1 = v; }
                else if (v > m2) { m2 = v; }
            }
            gs[g] = m1 + m2;
        }
        bool gsel[NGROUP] = {false,false,false,false,false,false,false,false};
        for (int r = 0; r < TOPKG; r++) {
            int bi = 0; float bv = -INFINITY;
            for (int g = 0; g < NGROUP; g++)
                if (!gsel[g] && gs[g] > bv) { bv = gs[g]; bi = g; }
            gsel[bi] = true;
        }
        int sel[TOPK]; float wgt[TOPK]; float sum = 0.f;
        for (int r = 0; r < TOPK; r++) {
            int bi = 0; float bv = -INFINITY;
            for (int e = 0; e < NE; e++) {
                const float sv = s[e];
                const float v = (sv == -INFINITY) ? -INFINITY
                               : (gsel[e >> 5] ? sv : 0.0f);
                if (v > bv) { bv = v; bi = e; }
            }
            sel[r] = bi;
            wgt[r] = s[bi] - bias[bi];   // unmasked sigmoid score
            s[bi]  = -INFINITY;
            sum += wgt[r];
        }
        const float scale = 2.5f / (sum + 1e-20f);
        const int gt = t0 + tid;
        #pragma unroll
        for (int r = 0; r < TOPK; r++) {
            out[(size_t)gt * TOPK + r] = wgt[r] * scale;
            out[(size_t)TOKENS * TOPK + (size_t)gt * TOPK + r] = (float)sel[r];
        }
    }
}

extern "C" void kernel_launch(void* const* d_in, const int* in_sizes, int n_in,
                              void* d_out, int out_size, void* d_ws, size_t ws_size,
                              hipStream_t stream) {
    const float* X  = (const float*)d_in[0];
    const float* W  = (const float*)d_in[1];
    const float* eb = (const float*)d_in[2];
    float* out = (float*)d_out;

    _Float16* wp   = (_Float16*)d_ws;
    float* partial = (float*)((char*)d_ws + WPLANES_BYTES);

    hipLaunchKernelGGL(prep_w, dim3(7, 256), dim3(128), 0, stream, W, wp);
    hipLaunchKernelGGL(gemm_kernel, dim3(TOKENS / TM * KSPLIT), dim3(256), 0, stream, X, wp, partial);
    hipLaunchKernelGGL(select_kernel, dim3(TOKENS / 32), dim3(256), 0, stream, partial, eb, out);
}